// Round 11
// baseline (412.685 us; speedup 1.0000x reference)
//
#include <hip/hip_runtime.h>
#include <hip/hip_bf16.h>

#define E_NUM 160000
#define NN 10000
#define PI_F 3.14159265358979323846f

using u16 = unsigned short;
using u32 = unsigned int;
typedef short bf16x8 __attribute__((ext_vector_type(8)));
typedef float f32x4 __attribute__((ext_vector_type(4)));
typedef u32 u32x4 __attribute__((ext_vector_type(4)));

__device__ __forceinline__ float silu_fast(float z) {
    return z * __builtin_amdgcn_rcpf(1.0f + __expf(-z));
}
__device__ __forceinline__ float bfb2f(u32 bits16) {
    return __builtin_bit_cast(float, bits16 << 16);
}
__device__ __forceinline__ u32 f2bfb(float f) {
    return (u32)__builtin_bit_cast(u16, __float2bfloat16(f));
}
__device__ __forceinline__ u32 pack2(float lo, float hi) {
    return f2bfb(lo) | (f2bfb(hi) << 16);
}

// ---------------- dtype detection (inputs fp32 vs bf16) ----------------
__global__ void k_detect(const u16* __restrict__ posraw, int* __restrict__ flag) {
    int i = blockIdx.x * 256 + threadIdx.x;
    if (i >= 15000) return;
    float v = bfb2f((u32)posraw[2 * i]);
    if (!(fabsf(v) < 1e4f)) atomicOr(flag, 1);
}

// ------ fused prep 1: dual-dtype ingest (1406 blocks) + sender hist (625) ------
__global__ void k_prep1(const void* s0, const void* s1, const void* s2,
                        const void* s3, const void* s4, const void* s5,
                        const void* s6, const void* s7, const void* s8,
                        float* __restrict__ dst, const int* __restrict__ flag,
                        const int* __restrict__ senders, int* __restrict__ counts) {
    int bid = blockIdx.x;
    if (bid < 1406) {
        int i = bid * 256 + threadIdx.x;
        if (i >= 359792) return;
        const void* src; int off;
        if      (i < 30000)  { src = s0; off = i; }
        else if (i < 36144)  { src = s1; off = i - 30000; }
        else if (i < 68912)  { src = s2; off = i - 36144; }
        else if (i < 73008)  { src = s3; off = i - 68912; }
        else if (i < 81200)  { src = s4; off = i - 73008; }
        else if (i < 277808) { src = s5; off = i - 81200; }
        else if (i < 343344) { src = s6; off = i - 277808; }
        else if (i < 359728) { src = s7; off = i - 343344; }
        else                 { src = s8; off = i - 359728; }
        if (*flag) dst[i] = ((const float*)src)[off];
        else       dst[i] = bfb2f((u32)((const u16*)src)[off]);
    } else {
        int e = (bid - 1406) * 256 + threadIdx.x;
        if (e < E_NUM) atomicAdd(&counts[senders[e]], 1);
    }
}

// ------- weight packer body: [K][N] fp32 -> INTERLEAVED hi/lo B-frag layout -------
// group g = (k>>3)*N + n; hi octet at g*16 + (k&7), lo octet at g*16 + 8 + (k&7).
__device__ __forceinline__ void pack_body(const float* __restrict__ W, int K, int Nshift,
                                          u16* __restrict__ pk, int i) {
    int total = K << Nshift;
    if (i >= total) return;
    int k = i >> Nshift, n = i & ((1 << Nshift) - 1);
    float w = W[i];
    u16 h = (u16)f2bfb(w);
    float r = w - bfb2f((u32)h);
    int idx = ((((k >> 3) << Nshift) + n) << 4) + (k & 7);
    pk[idx] = h; pk[idx + 8] = (u16)f2bfb(r);
}

// emb W1 body: rows 0..11 = hi(W), 12..23 = hi(W), 24..35 = lo(W), 36..63 = 0
__device__ __forceinline__ void pack_emb1_body(const float* __restrict__ W /*12x512*/,
                                               u16* __restrict__ pk, int i) {
    if (i >= 64 * 512) return;
    int k = i >> 9, n = i & 511;
    u16 out = 0;
    if (k < 24) {
        out = (u16)f2bfb(W[(k % 12) * 512 + n]);
    } else if (k < 36) {
        float w = W[(k - 24) * 512 + n];
        u16 h = (u16)f2bfb(w);
        out = (u16)f2bfb(w - bfb2f((u32)h));
    }
    pk[((((k >> 3) << 9) + n) << 4) + (k & 7)] = out;
}

// ------ fused prep 2: CSR fill (625 blocks) + ALL weight packs (1360) ------
__global__ void k_prep2(const int* __restrict__ senders, int* __restrict__ cursor,
                        int* __restrict__ edge_list,
                        const float* __restrict__ Wemb1, const float* __restrict__ Wemb2,
                        const float* __restrict__ Wenv, const float* __restrict__ Wv,
                        const float* __restrict__ Wmix, const float* __restrict__ Wlat1,
                        const float* __restrict__ Wlat2,
                        u16* __restrict__ e1pk, u16* __restrict__ e2pk,
                        u16* __restrict__ we0pk, u16* __restrict__ we1pk,
                        u16* __restrict__ wvpk, u16* __restrict__ wmpk,
                        u16* __restrict__ w1pk, u16* __restrict__ w2pk) {
    int bid = blockIdx.x;
    int t = threadIdx.x;
    if (bid < 625) {
        int e = bid * 256 + t;
        if (e >= E_NUM) return;
        int pos = atomicAdd(&cursor[senders[e]], 1);
        edge_list[pos] = e;
        return;
    }
    bid -= 625;
    if      (bid < 128)  pack_emb1_body(Wemb1, e1pk, bid * 256 + t);
    else if (bid < 256)  pack_body(Wemb2, 512, 6, e2pk, (bid - 128) * 256 + t);
    else if (bid < 272)  pack_body(Wenv, 64, 6, we0pk, (bid - 256) * 256 + t);
    else if (bid < 288)  pack_body(Wenv + 4096, 64, 6, we1pk, (bid - 272) * 256 + t);
    else if (bid < 304)  pack_body(Wv, 64, 6, wvpk, (bid - 288) * 256 + t);
    else if (bid < 336)  pack_body(Wmix, 64, 7, wmpk, (bid - 304) * 256 + t);
    else if (bid < 720)  pack_body(Wlat1, 192, 9, w1pk, (bid - 336) * 256 + t);
    else if (bid < 1104) pack_body(Wlat1 + 98304, 192, 9, w1pk + 196608, (bid - 720) * 256 + t);
    else if (bid < 1232) pack_body(Wlat2, 512, 6, w2pk, (bid - 1104) * 256 + t);
    else                 pack_body(Wlat2 + 32768, 512, 6, w2pk + 65536, (bid - 1232) * 256 + t);
}

// ---------------- CSR scan (also seeds cursor) ----------------
__global__ __launch_bounds__(1024) void k_scan(const int* __restrict__ counts,
                                               int* __restrict__ rowstart,
                                               int* __restrict__ cursor) {
    __shared__ int part[1024];
    int t = threadIdx.x;
    int base = t * 10;
    int local[10];
    int sum = 0;
    #pragma unroll
    for (int i = 0; i < 10; i++) {
        int v = (base + i < NN) ? counts[base + i] : 0;
        local[i] = sum; sum += v;
    }
    part[t] = sum;
    __syncthreads();
    for (int off = 1; off < 1024; off <<= 1) {
        int v = (t >= off) ? part[t - off] : 0;
        __syncthreads();
        part[t] += v;
        __syncthreads();
    }
    int pre = (t == 0) ? 0 : part[t - 1];
    #pragma unroll
    for (int i = 0; i < 10; i++)
        if (base + i < NN) {
            int v = pre + local[i];
            rowstart[base + i] = v;
            cursor[base + i] = v;
        }
    if (t == 1023) rowstart[NN] = part[1023];
}

// ---------------- geometry in SORTED edge space ----------------
// latin layout: group-packed. Groups 5..7 are identically ZERO -> not stored.
__global__ void k_geom(const float* __restrict__ posf, const int* __restrict__ species,
                       const int* __restrict__ senders, const int* __restrict__ receivers,
                       const int* __restrict__ edge_list,
                       int* __restrict__ ssend, int* __restrict__ srecv,
                       float* __restrict__ ux, float* __restrict__ uy, float* __restrict__ uz,
                       float* __restrict__ envb, u32* __restrict__ latin) {
    int e = blockIdx.x * 256 + threadIdx.x;
    if (e >= E_NUM) return;
    int orig = edge_list[e];
    int s = senders[orig], r = receivers[orig];
    ssend[e] = s; srecv[e] = r;
    float rx = posf[3 * r + 0] - posf[3 * s + 0];
    float ry = posf[3 * r + 1] - posf[3 * s + 1];
    float rz = posf[3 * r + 2] - posf[3 * s + 2];
    float d = sqrtf(rx * rx + ry * ry + rz * rz);
    float inv = 1.0f / fmaxf(d, 1e-6f);
    ux[e] = rx * inv; uy[e] = ry * inv; uz[e] = rz * inv;
    float xc = d * 0.5f;
    float env = 0.0f;
    if (xc < 1.0f) { float t = 1.0f - xc * xc; env = t * t; }
    envb[e] = env;
    float ft[12];
    float se = env * inv;
    #pragma unroll
    for (int n = 1; n <= 8; n++) ft[n - 1] = __sinf((float)n * PI_F * xc) * se;
    int ss = species[s], sr = species[r];
    ft[8] = (ss == 0) ? 1.0f : 0.0f;
    ft[9] = (ss == 1) ? 1.0f : 0.0f;
    ft[10] = (sr == 0) ? 1.0f : 0.0f;
    ft[11] = (sr == 1) ? 1.0f : 0.0f;
    u32 ch[20];
    #pragma unroll
    for (int i = 0; i < 20; i++) ch[i] = 0;
    #pragma unroll
    for (int j = 0; j < 6; j++) {
        u32 hp = f2bfb(ft[2 * j]) | (f2bfb(ft[2 * j + 1]) << 16);
        float l0 = ft[2 * j] - bfb2f(f2bfb(ft[2 * j]));
        float l1 = ft[2 * j + 1] - bfb2f(f2bfb(ft[2 * j + 1]));
        ch[j] = hp;
        ch[12 + j] = hp;
        ch[6 + j] = pack2(l0, l1);
    }
    #pragma unroll
    for (int g = 0; g < 5; g++) {
        u32x4 v = {ch[4 * g], ch[4 * g + 1], ch[4 * g + 2], ch[4 * g + 3]};
        *(u32x4*)(latin + (((size_t)g * E_NUM + e) << 2)) = v;
    }
}

// ---------------- rho gather (4x unrolled j-loop, bitwise-same order) ----------------
__global__ __launch_bounds__(256) void k_rho_gather(
    const float* __restrict__ we, const int* __restrict__ rowstart,
    const float* __restrict__ ux, const float* __restrict__ uy,
    const float* __restrict__ uz,
    float* __restrict__ rho0, float* __restrict__ rho1) {
    int wv = (blockIdx.x * 256 + threadIdx.x) >> 6;
    int c = threadIdx.x & 63;
    if (wv >= NN) return;
    int start = rowstart[wv], end = rowstart[wv + 1];
    float s0 = 0.0f, sx = 0.0f, sy = 0.0f, sz = 0.0f;
    int j = start;
    for (; j + 4 <= end; j += 4) {
        float w0 = we[(size_t)j * 64 + c];
        float w1 = we[(size_t)(j + 1) * 64 + c];
        float w2 = we[(size_t)(j + 2) * 64 + c];
        float w3 = we[(size_t)(j + 3) * 64 + c];
        float a0 = ux[j], b0 = uy[j], g0 = uz[j];
        float a1 = ux[j + 1], b1 = uy[j + 1], g1 = uz[j + 1];
        float a2 = ux[j + 2], b2 = uy[j + 2], g2 = uz[j + 2];
        float a3 = ux[j + 3], b3 = uy[j + 3], g3 = uz[j + 3];
        s0 += w0; sx = fmaf(w0, a0, sx); sy = fmaf(w0, b0, sy); sz = fmaf(w0, g0, sz);
        s0 += w1; sx = fmaf(w1, a1, sx); sy = fmaf(w1, b1, sy); sz = fmaf(w1, g1, sz);
        s0 += w2; sx = fmaf(w2, a2, sx); sy = fmaf(w2, b2, sy); sz = fmaf(w2, g2, sz);
        s0 += w3; sx = fmaf(w3, a3, sx); sy = fmaf(w3, b3, sy); sz = fmaf(w3, g3, sz);
    }
    for (; j < end; j++) {
        float w0 = we[(size_t)j * 64 + c];
        float a0 = ux[j], b0 = uy[j], g0 = uz[j];
        s0 += w0; sx = fmaf(w0, a0, sx); sy = fmaf(w0, b0, sy); sz = fmaf(w0, g0, sz);
    }
    const float inv3 = 1.0f / 3.0f;
    rho0[(size_t)wv * 64 + c] = s0 * inv3;
    rho1[(size_t)wv * 192 + 3 * c + 0] = sx * inv3;
    rho1[(size_t)wv * 192 + 3 * c + 1] = sy * inv3;
    rho1[(size_t)wv * 192 + 3 * c + 2] = sz * inv3;
}

// =====================================================================
// MFMA MLP v21 = v20 (R10, measured 405.3 us total — best) + s_setprio
// wrapped around the prologue mini-GEMMs (Wv, Wmix) and the FUSEWE
// epilogue we-GEMM (T5 mechanism, same regime that gave R6's win on the
// main-loop clusters; previously only the main loop was wrapped).
// All other code identical. Spill tripwire: FETCH ~36 MB, VGPR <= 64.
// Structural note: occupancy (R2/R4), barriers (R5), wave-mapping (R9)
// levers all measured-closed; per-dispatch floor of this MFMA shape is
// ~120 us at 74% combined issue. Next step beyond this kernel would be
// a 32x32x16-MFMA fragment rewrite (needs a refcheck loop).
// =====================================================================
template<int KSTEPS, int MODE, int HASLO, int FUSEWE, int STAGE>
__global__ __launch_bounds__(512, 4) void k_mlp(
    const u32* __restrict__ latin,
    const u16* __restrict__ W1pk, const u16* __restrict__ W2pk,
    const float* __restrict__ envb,
    u32* __restrict__ xout,
    const u16* __restrict__ wepk,
    float* __restrict__ webuf,
    const u32* __restrict__ xin,
    const u32* __restrict__ x0t,
    const int* __restrict__ ssend,
    const float* __restrict__ ux, const float* __restrict__ uy,
    const float* __restrict__ uz,
    const float* __restrict__ rho0A, const float* __restrict__ rho1A,
    const float* __restrict__ rho0B, const float* __restrict__ rho1B,
    const u16* __restrict__ wvpk, const u16* __restrict__ wmpk,
    const float* __restrict__ WoutP, const int* __restrict__ srecv,
    float* __restrict__ node_acc) {
    constexpr int ROWDW = KSTEPS * 16;
    constexpr int INAREG = KSTEPS * 4096;
    // transpose region (STAGE2): tbA 16640 + mb 16640 = 33280 >= 32768 hA dbuf
    constexpr int SMEMSZ = INAREG + ((STAGE == 2) ? (2 * 16640) : 32768);
    __shared__ __align__(16) char smem[SMEMSZ];
    u32* inA = (u32*)smem;
    u16* hA  = (u16*)(smem + INAREG);           // 2 x 16 KB double buffer (MLP)
    float* tbA = (float*)(smem + INAREG);       // 64x65 fp32 (a transpose, prologue)
    u16* mb   = (u16*)(smem + INAREG + 16640);  // m1/m2 interleaved bf16 (prologue)
    u32* mb32 = (u32*)(smem + INAREG + 16640);
    u32* xt0  = (u32*)(smem + INAREG + 16640);  // x0 tile (dies before mb writes)
    int lane = threadIdx.x & 63;
    int sub = threadIdx.x >> 6;
    int w = __builtin_amdgcn_readfirstlane(sub);
    int l15 = lane & 15, quad = lane >> 4;
    int e0 = blockIdx.x * 64;
    int e = e0 + lane;

    if (STAGE == 0) {
        // groups 5..7 of latin are identically zero (not stored)
        u32x4 v = (u32x4){0, 0, 0, 0};
        if (w < 5) v = *(const u32x4*)(latin + (((size_t)w * E_NUM + e) << 2));
        int slot = (w ^ lane) & 7;
        *(u32x4*)(&inA[lane * ROWDW + slot * 4]) = v;
        __syncthreads();
    } else {
        // stage xin chunk-group w -> inA (one dwordx4)
        {
            int c = w;
            u32x4 v = *(const u32x4*)(xin + (((size_t)c * E_NUM + e) << 2));
            int slot = (c & ~7) | ((c ^ lane) & 7);
            *(u32x4*)(&inA[lane * ROWDW + slot * 4]) = v;
        }
        if (STAGE == 2) {
            u32x4 v = *(const u32x4*)(x0t + (((size_t)w * E_NUM + e) << 2));
            int slot = (w ^ lane) & 7;
            *(u32x4*)(&xt0[lane * 32 + slot * 4]) = v;
        }
        __syncthreads();
        // mini-GEMM a = x0 @ Wv
        int mt = w & 3;
        int ntbA = (w >> 2) * 2;
        f32x4 accA[2];
        accA[0] = (f32x4){0.f, 0.f, 0.f, 0.f};
        accA[1] = (f32x4){0.f, 0.f, 0.f, 0.f};
        __builtin_amdgcn_s_setprio(1);
        #pragma unroll
        for (int ks = 0; ks < 2; ks++) {
            int c = ks * 4 + quad;
            int m = mt * 16 + l15;
            bf16x8 af;
            if (STAGE == 1) {
                int slot = (c & ~7) | ((c ^ m) & 7);
                af = *(const bf16x8*)(&inA[m * ROWDW + slot * 4]);
            } else {
                int slot = (c ^ m) & 7;
                af = *(const bf16x8*)(&xt0[m * 32 + slot * 4]);
            }
            #pragma unroll
            for (int nti = 0; nti < 2; nti++) {
                int n = (ntbA + nti) * 16 + l15;
                const u16* bp = wvpk + ((((size_t)c << 6) + n) << 4);
                bf16x8 bh = *(const bf16x8*)(bp);
                accA[nti] = __builtin_amdgcn_mfma_f32_16x16x32_bf16(af, bh, accA[nti], 0, 0, 0);
                bf16x8 bl = *(const bf16x8*)(bp + 8);
                accA[nti] = __builtin_amdgcn_mfma_f32_16x16x32_bf16(af, bl, accA[nti], 0, 0, 0);
            }
        }
        __builtin_amdgcn_s_setprio(0);
        // mini-GEMM m = x1 @ Wmix (STAGE==2)
        f32x4 accM[4];
        if (STAGE == 2) {
            #pragma unroll
            for (int i = 0; i < 4; i++) accM[i] = (f32x4){0.f, 0.f, 0.f, 0.f};
            int nbM = (w >> 2) * 4;
            __builtin_amdgcn_s_setprio(1);
            #pragma unroll
            for (int ks = 0; ks < 2; ks++) {
                int c = ks * 4 + quad;
                int m = mt * 16 + l15;
                int slot = (c & ~7) | ((c ^ m) & 7);
                bf16x8 af = *(const bf16x8*)(&inA[m * ROWDW + slot * 4]);
                #pragma unroll
                for (int nti = 0; nti < 4; nti++) {
                    int n = (nbM + nti) * 16 + l15;
                    const u16* bp = wmpk + ((((size_t)c << 7) + n) << 4);
                    bf16x8 bh = *(const bf16x8*)(bp);
                    accM[nti] = __builtin_amdgcn_mfma_f32_16x16x32_bf16(af, bh, accM[nti], 0, 0, 0);
                    bf16x8 bl = *(const bf16x8*)(bp + 8);
                    accM[nti] = __builtin_amdgcn_mfma_f32_16x16x32_bf16(af, bl, accM[nti], 0, 0, 0);
                }
            }
            __builtin_amdgcn_s_setprio(0);
        }
        __syncthreads();   // all GEMM LDS reads done (xt0 dead)
        // ---- single transpose round: a -> tbA (fp32), m1/m2 -> mb (bf16 halves)
        #pragma unroll
        for (int nti = 0; nti < 2; nti++) {
            #pragma unroll
            for (int r = 0; r < 4; r++) {
                int rowD = mt * 16 + quad * 4 + r;
                int colD = (ntbA + nti) * 16 + l15;
                tbA[colD * 65 + rowD] = accA[nti][r];
            }
        }
        if (STAGE == 2) {
            int sel = (w >= 4) ? 1 : 0;
            #pragma unroll
            for (int nti = 0; nti < 4; nti++) {
                #pragma unroll
                for (int r = 0; r < 4; r++) {
                    int rowD = mt * 16 + quad * 4 + r;
                    int colD = nti * 16 + l15;
                    mb[((colD * 65 + rowD) << 1) + sel] = (u16)f2bfb(accM[nti][r]);
                }
            }
        }
        __syncthreads();
        int c0 = w * 8;
        float av[8], m1v[8], m2v[8];
        #pragma unroll
        for (int i = 0; i < 8; i++) av[i] = tbA[(c0 + i) * 65 + lane];
        if (STAGE == 2) {
            #pragma unroll
            for (int i = 0; i < 8; i++) {
                u32 pv = mb32[(c0 + i) * 65 + lane];
                m1v[i] = bfb2f(pv & 0xffffu);
                m2v[i] = bfb2f(pv >> 16);
            }
        }
        // per-lane tp math + gathers
        int s = ssend[e];
        float u0 = ux[e], u1 = uy[e], u2 = uz[e];
        float ts[8], rr[8];
        if (STAGE == 1) {
            const float* r1 = rho1A + (size_t)s * 192;
            const float* r0 = rho0A + (size_t)s * 64;
            #pragma unroll
            for (int i = 0; i < 8; i++) {
                int c = c0 + i;
                float dot = u0 * r1[3 * c] + u1 * r1[3 * c + 1] + u2 * r1[3 * c + 2];
                ts[i] = av[i] * dot;
                rr[i] = r0[c];
            }
        } else {
            const float* r1A = rho1A + (size_t)s * 192;
            const float* r0A = rho0A + (size_t)s * 64;
            const float* r1B = rho1B + (size_t)s * 192;
            const float* r0B = rho0B + (size_t)s * 64;
            #pragma unroll
            for (int i = 0; i < 8; i++) {
                int c = c0 + i;
                float v0 = av[i] * u0, v1 = av[i] * u1, v2 = av[i] * u2;
                float aA0 = r1A[3 * c], aA1 = r1A[3 * c + 1], aA2 = r1A[3 * c + 2];
                float rc = r0A[c];
                float w0 = m1v[i] * v0 * rc + m2v[i] * (v1 * aA2 - v2 * aA1);
                float w1 = m1v[i] * v1 * rc + m2v[i] * (v2 * aA0 - v0 * aA2);
                float w2 = m1v[i] * v2 * rc + m2v[i] * (v0 * aA1 - v1 * aA0);
                ts[i] = w0 * r1B[3 * c] + w1 * r1B[3 * c + 1] + w2 * r1B[3 * c + 2];
                rr[i] = r0B[c];
            }
        }
        u32x4 tv, rv;
        #pragma unroll
        for (int j = 0; j < 4; j++) {
            tv[j] = pack2(ts[2 * j], ts[2 * j + 1]);
            rv[j] = pack2(rr[2 * j], rr[2 * j + 1]);
        }
        {
            int c = 8 + w;
            int slot = (c & ~7) | ((c ^ lane) & 7);
            *(u32x4*)(&inA[lane * ROWDW + slot * 4]) = tv;
        }
        {
            int c = 16 + w;
            int slot = (c & ~7) | ((c ^ lane) & 7);
            *(u32x4*)(&inA[lane * ROWDW + slot * 4]) = rv;
        }
        __syncthreads();
    }

    // ======== main MLP: software-pipelined, hA double-buffered ========
    f32x4 acc2[2];
    acc2[0] = (f32x4){0.f, 0.f, 0.f, 0.f};
    acc2[1] = (f32x4){0.f, 0.f, 0.f, 0.f};
    int nt2 = w & 3;
    int mt2a = (w >> 2) * 2;
    int p = 0;

    #pragma unroll
    for (int it = 0; it < 5; it++) {
        f32x4 acc[4];
        if (it < 4) {
            #pragma unroll
            for (int mt = 0; mt < 4; mt++) acc[mt] = (f32x4){0.f, 0.f, 0.f, 0.f};
            __builtin_amdgcn_s_setprio(1);
            #pragma unroll
            for (int ks = 0; ks < KSTEPS; ks++) {
                int c = ks * 4 + quad;
                bf16x8 afr[4];
                #pragma unroll
                for (int mt = 0; mt < 4; mt++) {
                    int m = mt * 16 + l15;
                    int slot = (c & ~7) | ((c ^ m) & 7);
                    afr[mt] = *(const bf16x8*)(&inA[m * ROWDW + slot * 4]);
                }
                int n = it * 128 + w * 16 + l15;
                const u16* bp = W1pk + ((((size_t)c << 9) + n) << 4);
                bf16x8 bh = *(const bf16x8*)(bp);
                #pragma unroll
                for (int mt = 0; mt < 4; mt++)
                    acc[mt] = __builtin_amdgcn_mfma_f32_16x16x32_bf16(afr[mt], bh, acc[mt], 0, 0, 0);
                if (HASLO) {
                    bf16x8 bl = *(const bf16x8*)(bp + 8);
                    #pragma unroll
                    for (int mt = 0; mt < 4; mt++)
                        acc[mt] = __builtin_amdgcn_mfma_f32_16x16x32_bf16(afr[mt], bl, acc[mt], 0, 0, 0);
                }
            }
            __builtin_amdgcn_s_setprio(0);
        }
        if (it > 0) {
            const u16* hAr = hA + (p ^ 1) * 8192;
            __builtin_amdgcn_s_setprio(1);
            #pragma unroll
            for (int ks = 0; ks < 4; ks++) {
                int c = ks * 4 + quad;
                int m0 = mt2a * 16 + l15;
                int m1i = m0 + 16;
                int s0 = (c & 8) | ((c ^ m0) & 7);
                int s1 = (c & 8) | ((c ^ m1i) & 7);
                bf16x8 a0 = *(const bf16x8*)(&hAr[m0 * 128 + s0 * 8]);
                bf16x8 a1 = *(const bf16x8*)(&hAr[m1i * 128 + s1 * 8]);
                const u16* bp = W2pk + ((((size_t)((it - 1) * 16 + c) << 6) + nt2 * 16 + l15) << 4);
                bf16x8 bh = *(const bf16x8*)(bp);
                acc2[0] = __builtin_amdgcn_mfma_f32_16x16x32_bf16(a0, bh, acc2[0], 0, 0, 0);
                acc2[1] = __builtin_amdgcn_mfma_f32_16x16x32_bf16(a1, bh, acc2[1], 0, 0, 0);
                bf16x8 bl = *(const bf16x8*)(bp + 8);
                acc2[0] = __builtin_amdgcn_mfma_f32_16x16x32_bf16(a0, bl, acc2[0], 0, 0, 0);
                acc2[1] = __builtin_amdgcn_mfma_f32_16x16x32_bf16(a1, bl, acc2[1], 0, 0, 0);
            }
            __builtin_amdgcn_s_setprio(0);
        }
        if (it < 4) {
            u16* hAw = hA + p * 8192;
            int kh = w * 16 + l15;
            int c = kh >> 3;
            #pragma unroll
            for (int mt = 0; mt < 4; mt++) {
                #pragma unroll
                for (int r = 0; r < 4; r++) {
                    int m = mt * 16 + quad * 4 + r;
                    float s = silu_fast(acc[mt][r]);
                    int slot = (c & 8) | ((c ^ m) & 7);
                    hAw[m * 128 + slot * 8 + (kh & 7)] = (u16)f2bfb(s);
                }
            }
            __syncthreads();
        }
        p ^= 1;
    }
    // read xprev (chunks 0..7 hold current-layer x) from LDS before epi overlay
    float xo[8];
    if (MODE) {
        int c = w;
        int slot = (c & ~7) | ((c ^ lane) & 7);
        #pragma unroll
        for (int i = 0; i < 4; i++) {
            u32 pv = inA[lane * ROWDW + slot * 4 + i];
            xo[2 * i]     = bfb2f(pv & 0xffffu);
            xo[2 * i + 1] = bfb2f(pv >> 16);
        }
    }
    __syncthreads();
    float* epi = (float*)inA;   // 64 x 65 fp32 overlay (16640 B of INAREG)
    #pragma unroll
    for (int mi = 0; mi < 2; mi++) {
        #pragma unroll
        for (int r = 0; r < 4; r++) {
            int m = (mt2a + mi) * 16 + quad * 4 + r;
            int c = nt2 * 16 + l15;
            epi[c * 65 + m] = acc2[mi][r];
        }
    }
    __syncthreads();
    float env = envb[e];
    const float is2 = 0.70710678118654752f;
    float resv[8];
    #pragma unroll
    for (int i = 0; i < 8; i++) {
        int c = w * 8 + i;
        float v = epi[c * 65 + lane];
        float res;
        if (MODE) res = (xo[i] + v * env) * is2;
        else      res = v * env;
        resv[i] = res;
        if (FUSEWE) epi[c * 65 + lane] = res;
    }
    if (STAGE != 2) {
        u32x4 tv;
        #pragma unroll
        for (int j = 0; j < 4; j++) tv[j] = pack2(resv[2 * j], resv[2 * j + 1]);
        *(u32x4*)(xout + (((size_t)w * E_NUM + e) << 2)) = tv;
    }
    if (STAGE == 2) {
        // fused readout: e_edge = dot(x1, Wout) * env / 3 -> node_acc[srecv]
        float* red = (float*)(smem + 20480);   // disjoint from epi (<16640)
        float pd = 0.0f;
        #pragma unroll
        for (int i = 0; i < 8; i++) pd = fmaf(resv[i], WoutP[w * 8 + i], pd);
        red[w * 64 + lane] = pd;
        __syncthreads();
        if (w == 0) {
            float sum = 0.0f;
            #pragma unroll
            for (int ww = 0; ww < 8; ww++) sum += red[ww * 64 + lane];
            atomicAdd(&node_acc[srecv[e]], sum * env * (1.0f / 3.0f));
        }
    }
    if (FUSEWE) {
        __syncthreads();
        int mt = w & 3;
        int ntb = (w >> 2) * 2;
        f32x4 accw[2];
        accw[0] = (f32x4){0.f, 0.f, 0.f, 0.f};
        accw[1] = (f32x4){0.f, 0.f, 0.f, 0.f};
        __builtin_amdgcn_s_setprio(1);
        #pragma unroll
        for (int ks = 0; ks < 2; ks++) {
            bf16x8 af;
            #pragma unroll
            for (int j = 0; j < 8; j++)
                af[j] = (short)f2bfb(epi[(ks * 32 + quad * 8 + j) * 65 + mt * 16 + l15]);
            #pragma unroll
            for (int nti = 0; nti < 2; nti++) {
                int n4 = (ntb + nti) * 16 + l15;
                const u16* bp = wepk + ((((size_t)(ks * 4 + quad) << 6) + n4) << 4);
                bf16x8 bh = *(const bf16x8*)(bp);
                accw[nti] = __builtin_amdgcn_mfma_f32_16x16x32_bf16(af, bh, accw[nti], 0, 0, 0);
                bf16x8 bl = *(const bf16x8*)(bp + 8);
                accw[nti] = __builtin_amdgcn_mfma_f32_16x16x32_bf16(af, bl, accw[nti], 0, 0, 0);
            }
        }
        __builtin_amdgcn_s_setprio(0);
        #pragma unroll
        for (int nti = 0; nti < 2; nti++) {
            #pragma unroll
            for (int r = 0; r < 4; r++) {
                int rowD = mt * 16 + quad * 4 + r;
                int colD = (ntb + nti) * 16 + l15;
                webuf[(size_t)(e0 + rowD) * 64 + colD] = accw[nti][r];
            }
        }
    }
}

__global__ void k_out(const float* __restrict__ node_acc, void* __restrict__ out,
                      const int* __restrict__ flag) {
    int n = blockIdx.x * 256 + threadIdx.x;
    if (n >= NN) return;
    float v = node_acc[n];
    if (*flag) ((float*)out)[n] = v;
    else       ((u16*)out)[n] = (u16)f2bfb(v);
}

extern "C" void kernel_launch(void* const* d_in, const int* in_sizes, int n_in,
                              void* d_out, int out_size, void* d_ws, size_t ws_size,
                              hipStream_t stream) {
    const void* posr   = d_in[0];
    const void* Wemb1r = d_in[1];
    const void* Wemb2r = d_in[2];
    const void* Wvr    = d_in[3];
    const void* Wenvr  = d_in[4];
    const void* Wlat1r = d_in[5];
    const void* Wlat2r = d_in[6];
    const void* Wmixr  = d_in[7];
    const void* Woutr  = d_in[8];
    const int* species   = (const int*)d_in[9];
    const int* senders   = (const int*)d_in[10];
    const int* receivers = (const int*)d_in[11];

    char* p = (char*)d_ws;
    auto alloc = [&](size_t bytes) -> void* {
        void* rp = (void*)p;
        p += (bytes + 255) & ~(size_t)255;
        return rp;
    };
    int*   flag  = (int*)alloc(4);
    float* wbuf  = (float*)alloc(359792 * 4);
    float* posf  = wbuf;
    float* Wemb1 = wbuf + 30000;
    float* Wemb2 = wbuf + 36144;
    float* Wv    = wbuf + 68912;
    float* Wenv  = wbuf + 73008;
    float* Wlat1 = wbuf + 81200;
    float* Wlat2 = wbuf + 277808;
    float* Wmix  = wbuf + 343344;
    float* Wout  = wbuf + 359728;
    const size_t E = E_NUM;
    float* ux   = (float*)alloc(E * 4);
    float* uy   = (float*)alloc(E * 4);
    float* uz   = (float*)alloc(E * 4);
    float* envb = (float*)alloc(E * 4);
    float* rho0A = (float*)alloc((size_t)NN * 64 * 4);
    float* rho1A = (float*)alloc((size_t)NN * 192 * 4);
    float* rho0B = (float*)alloc((size_t)NN * 64 * 4);
    float* rho1B = (float*)alloc((size_t)NN * 192 * 4);
    float* node_acc = (float*)alloc((size_t)NN * 4);
    int* counts    = (int*)alloc((size_t)NN * 4);
    int* rowstart  = (int*)alloc((size_t)(NN + 1) * 4);
    int* cursor    = (int*)alloc((size_t)NN * 4);
    int* edge_list = (int*)alloc(E * 4);
    int* ssend     = (int*)alloc(E * 4);
    int* srecv     = (int*)alloc(E * 4);
    void* unionbuf = alloc(96 * E * 4);
    u32*   latin = (u32*)unionbuf;
    float* webuf = (float*)unionbuf + (size_t)32 * E;
    u32* x0 = (u32*)alloc(32 * E * 4);   // group-packed: 8 groups x E x u32x4
    u32* x1 = (u32*)alloc(32 * E * 4);
    // interleaved hi/lo packed weights
    u16* w1pk = (u16*)alloc(2 * 196608 * 2);   // 2 layers x 192x512 x (hi+lo)
    u16* w2pk = (u16*)alloc(2 * 65536 * 2);    // 2 layers x 512x64 x (hi+lo)
    u16* e1pk = (u16*)alloc(65536 * 2);        // emb W1 (hi-only slots used)
    u16* e2pk = (u16*)alloc(65536 * 2);        // emb W2
    u16* we0pk = (u16*)alloc(8192 * 2);
    u16* we1pk = (u16*)alloc(8192 * 2);
    u16* wvpk  = (u16*)alloc(8192 * 2);
    u16* wmpk  = (u16*)alloc(16384 * 2);

    hipMemsetAsync(flag, 0, 4, stream);
    hipMemsetAsync(counts, 0, (size_t)NN * 4, stream);
    hipMemsetAsync(node_acc, 0, (size_t)NN * 4, stream);

    k_detect<<<(15000 + 255) / 256, 256, 0, stream>>>((const u16*)posr, flag);

    // fused: dual-dtype ingest + sender histogram
    k_prep1<<<2031, 256, 0, stream>>>(
        posr, Wemb1r, Wemb2r, Wvr, Wenvr, Wlat1r, Wlat2r, Wmixr, Woutr,
        wbuf, flag, senders, counts);

    // scan writes rowstart AND cursor
    k_scan<<<1, 1024, 0, stream>>>(counts, rowstart, cursor);

    // fused: CSR fill + all weight packs
    k_prep2<<<1985, 256, 0, stream>>>(
        senders, cursor, edge_list,
        Wemb1, Wemb2, Wenv, Wv, Wmix, Wlat1, Wlat2,
        e1pk, e2pk, we0pk, we1pk, wvpk, wmpk, w1pk, w2pk);

    // embedding + fused layer-0 we
    k_geom<<<625, 256, 0, stream>>>(posf, species, senders, receivers, edge_list,
                                    ssend, srecv, ux, uy, uz, envb, latin);
    k_mlp<2, 0, 0, 1, 0><<<2500, 512, 0, stream>>>(
        latin, e1pk, e2pk, envb, x0, we0pk, webuf,
        nullptr, nullptr, nullptr, nullptr, nullptr, nullptr,
        nullptr, nullptr, nullptr, nullptr, nullptr, nullptr,
        nullptr, nullptr, nullptr);

    // layer 0 (fused stage) + fused layer-1 we
    k_rho_gather<<<2500, 256, 0, stream>>>(webuf, rowstart, ux, uy, uz,
                                           rho0A, rho1A);
    k_mlp<6, 1, 1, 1, 1><<<2500, 512, 0, stream>>>(
        nullptr, w1pk, w2pk, envb, x1, we1pk, webuf,
        x0, nullptr, ssend, ux, uy, uz, rho0A, rho1A, nullptr, nullptr,
        wvpk, nullptr, nullptr, nullptr, nullptr);

    // layer 1 (fused stage, compact m transpose) + FUSED READOUT
    k_rho_gather<<<2500, 256, 0, stream>>>(webuf, rowstart, ux, uy, uz,
                                           rho0B, rho1B);
    k_mlp<6, 1, 1, 0, 2><<<2500, 512, 0, stream>>>(
        nullptr, w1pk + 196608, w2pk + 65536, envb, nullptr, nullptr, nullptr,
        x1, x0, ssend, ux, uy, uz, rho0A, rho1A, rho0B, rho1B,
        wvpk, wmpk, Wout, srecv, node_acc);

    k_out<<<(NN + 255) / 256, 256, 0, stream>>>(node_acc, d_out, flag);
}

// Round 12
// 398.892 us; speedup vs baseline: 1.0346x; 1.0346x over previous
//
#include <hip/hip_runtime.h>
#include <hip/hip_bf16.h>

#define E_NUM 160000
#define NN 10000
#define PI_F 3.14159265358979323846f

using u16 = unsigned short;
using u32 = unsigned int;
typedef short bf16x8 __attribute__((ext_vector_type(8)));
typedef float f32x4 __attribute__((ext_vector_type(4)));
typedef u32 u32x4 __attribute__((ext_vector_type(4)));

__device__ __forceinline__ float silu_fast(float z) {
    return z * __builtin_amdgcn_rcpf(1.0f + __expf(-z));
}
__device__ __forceinline__ float bfb2f(u32 bits16) {
    return __builtin_bit_cast(float, bits16 << 16);
}
__device__ __forceinline__ u32 f2bfb(float f) {
    return (u32)__builtin_bit_cast(u16, __float2bfloat16(f));
}
__device__ __forceinline__ u32 pack2(float lo, float hi) {
    return f2bfb(lo) | (f2bfb(hi) << 16);
}

// ---------------- dtype detection (inputs fp32 vs bf16) ----------------
__global__ void k_detect(const u16* __restrict__ posraw, int* __restrict__ flag) {
    int i = blockIdx.x * 256 + threadIdx.x;
    if (i >= 15000) return;
    float v = bfb2f((u32)posraw[2 * i]);
    if (!(fabsf(v) < 1e4f)) atomicOr(flag, 1);
}

// ------ fused prep 1: dual-dtype ingest (1406 blocks) + sender hist (625) ------
__global__ void k_prep1(const void* s0, const void* s1, const void* s2,
                        const void* s3, const void* s4, const void* s5,
                        const void* s6, const void* s7, const void* s8,
                        float* __restrict__ dst, const int* __restrict__ flag,
                        const int* __restrict__ senders, int* __restrict__ counts) {
    int bid = blockIdx.x;
    if (bid < 1406) {
        int i = bid * 256 + threadIdx.x;
        if (i >= 359792) return;
        const void* src; int off;
        if      (i < 30000)  { src = s0; off = i; }
        else if (i < 36144)  { src = s1; off = i - 30000; }
        else if (i < 68912)  { src = s2; off = i - 36144; }
        else if (i < 73008)  { src = s3; off = i - 68912; }
        else if (i < 81200)  { src = s4; off = i - 73008; }
        else if (i < 277808) { src = s5; off = i - 81200; }
        else if (i < 343344) { src = s6; off = i - 277808; }
        else if (i < 359728) { src = s7; off = i - 343344; }
        else                 { src = s8; off = i - 359728; }
        if (*flag) dst[i] = ((const float*)src)[off];
        else       dst[i] = bfb2f((u32)((const u16*)src)[off]);
    } else {
        int e = (bid - 1406) * 256 + threadIdx.x;
        if (e < E_NUM) atomicAdd(&counts[senders[e]], 1);
    }
}

// ------- weight packer body: [K][N] fp32 -> INTERLEAVED hi/lo B-frag layout -------
// group g = (k>>3)*N + n; hi octet at g*16 + (k&7), lo octet at g*16 + 8 + (k&7).
__device__ __forceinline__ void pack_body(const float* __restrict__ W, int K, int Nshift,
                                          u16* __restrict__ pk, int i) {
    int total = K << Nshift;
    if (i >= total) return;
    int k = i >> Nshift, n = i & ((1 << Nshift) - 1);
    float w = W[i];
    u16 h = (u16)f2bfb(w);
    float r = w - bfb2f((u32)h);
    int idx = ((((k >> 3) << Nshift) + n) << 4) + (k & 7);
    pk[idx] = h; pk[idx + 8] = (u16)f2bfb(r);
}

// emb W1 body: rows 0..11 = hi(W), 12..23 = hi(W), 24..35 = lo(W), 36..63 = 0
__device__ __forceinline__ void pack_emb1_body(const float* __restrict__ W /*12x512*/,
                                               u16* __restrict__ pk, int i) {
    if (i >= 64 * 512) return;
    int k = i >> 9, n = i & 511;
    u16 out = 0;
    if (k < 24) {
        out = (u16)f2bfb(W[(k % 12) * 512 + n]);
    } else if (k < 36) {
        float w = W[(k - 24) * 512 + n];
        u16 h = (u16)f2bfb(w);
        out = (u16)f2bfb(w - bfb2f((u32)h));
    }
    pk[((((k >> 3) << 9) + n) << 4) + (k & 7)] = out;
}

// ------ fused prep 2: CSR fill (625 blocks) + ALL weight packs (1360) ------
__global__ void k_prep2(const int* __restrict__ senders, int* __restrict__ cursor,
                        int* __restrict__ edge_list,
                        const float* __restrict__ Wemb1, const float* __restrict__ Wemb2,
                        const float* __restrict__ Wenv, const float* __restrict__ Wv,
                        const float* __restrict__ Wmix, const float* __restrict__ Wlat1,
                        const float* __restrict__ Wlat2,
                        u16* __restrict__ e1pk, u16* __restrict__ e2pk,
                        u16* __restrict__ we0pk, u16* __restrict__ we1pk,
                        u16* __restrict__ wvpk, u16* __restrict__ wmpk,
                        u16* __restrict__ w1pk, u16* __restrict__ w2pk) {
    int bid = blockIdx.x;
    int t = threadIdx.x;
    if (bid < 625) {
        int e = bid * 256 + t;
        if (e >= E_NUM) return;
        int pos = atomicAdd(&cursor[senders[e]], 1);
        edge_list[pos] = e;
        return;
    }
    bid -= 625;
    if      (bid < 128)  pack_emb1_body(Wemb1, e1pk, bid * 256 + t);
    else if (bid < 256)  pack_body(Wemb2, 512, 6, e2pk, (bid - 128) * 256 + t);
    else if (bid < 272)  pack_body(Wenv, 64, 6, we0pk, (bid - 256) * 256 + t);
    else if (bid < 288)  pack_body(Wenv + 4096, 64, 6, we1pk, (bid - 272) * 256 + t);
    else if (bid < 304)  pack_body(Wv, 64, 6, wvpk, (bid - 288) * 256 + t);
    else if (bid < 336)  pack_body(Wmix, 64, 7, wmpk, (bid - 304) * 256 + t);
    else if (bid < 720)  pack_body(Wlat1, 192, 9, w1pk, (bid - 336) * 256 + t);
    else if (bid < 1104) pack_body(Wlat1 + 98304, 192, 9, w1pk + 196608, (bid - 720) * 256 + t);
    else if (bid < 1232) pack_body(Wlat2, 512, 6, w2pk, (bid - 1104) * 256 + t);
    else                 pack_body(Wlat2 + 32768, 512, 6, w2pk + 65536, (bid - 1232) * 256 + t);
}

// ---------------- CSR scan (also seeds cursor) ----------------
__global__ __launch_bounds__(1024) void k_scan(const int* __restrict__ counts,
                                               int* __restrict__ rowstart,
                                               int* __restrict__ cursor) {
    __shared__ int part[1024];
    int t = threadIdx.x;
    int base = t * 10;
    int local[10];
    int sum = 0;
    #pragma unroll
    for (int i = 0; i < 10; i++) {
        int v = (base + i < NN) ? counts[base + i] : 0;
        local[i] = sum; sum += v;
    }
    part[t] = sum;
    __syncthreads();
    for (int off = 1; off < 1024; off <<= 1) {
        int v = (t >= off) ? part[t - off] : 0;
        __syncthreads();
        part[t] += v;
        __syncthreads();
    }
    int pre = (t == 0) ? 0 : part[t - 1];
    #pragma unroll
    for (int i = 0; i < 10; i++)
        if (base + i < NN) {
            int v = pre + local[i];
            rowstart[base + i] = v;
            cursor[base + i] = v;
        }
    if (t == 1023) rowstart[NN] = part[1023];
}

// ---------------- geometry in SORTED edge space ----------------
// latin layout: group-packed. Groups 5..7 are identically ZERO -> not stored.
__global__ void k_geom(const float* __restrict__ posf, const int* __restrict__ species,
                       const int* __restrict__ senders, const int* __restrict__ receivers,
                       const int* __restrict__ edge_list,
                       int* __restrict__ ssend, int* __restrict__ srecv,
                       float* __restrict__ ux, float* __restrict__ uy, float* __restrict__ uz,
                       float* __restrict__ envb, u32* __restrict__ latin) {
    int e = blockIdx.x * 256 + threadIdx.x;
    if (e >= E_NUM) return;
    int orig = edge_list[e];
    int s = senders[orig], r = receivers[orig];
    ssend[e] = s; srecv[e] = r;
    float rx = posf[3 * r + 0] - posf[3 * s + 0];
    float ry = posf[3 * r + 1] - posf[3 * s + 1];
    float rz = posf[3 * r + 2] - posf[3 * s + 2];
    float d = sqrtf(rx * rx + ry * ry + rz * rz);
    float inv = 1.0f / fmaxf(d, 1e-6f);
    ux[e] = rx * inv; uy[e] = ry * inv; uz[e] = rz * inv;
    float xc = d * 0.5f;
    float env = 0.0f;
    if (xc < 1.0f) { float t = 1.0f - xc * xc; env = t * t; }
    envb[e] = env;
    float ft[12];
    float se = env * inv;
    #pragma unroll
    for (int n = 1; n <= 8; n++) ft[n - 1] = __sinf((float)n * PI_F * xc) * se;
    int ss = species[s], sr = species[r];
    ft[8] = (ss == 0) ? 1.0f : 0.0f;
    ft[9] = (ss == 1) ? 1.0f : 0.0f;
    ft[10] = (sr == 0) ? 1.0f : 0.0f;
    ft[11] = (sr == 1) ? 1.0f : 0.0f;
    u32 ch[20];
    #pragma unroll
    for (int i = 0; i < 20; i++) ch[i] = 0;
    #pragma unroll
    for (int j = 0; j < 6; j++) {
        u32 hp = f2bfb(ft[2 * j]) | (f2bfb(ft[2 * j + 1]) << 16);
        float l0 = ft[2 * j] - bfb2f(f2bfb(ft[2 * j]));
        float l1 = ft[2 * j + 1] - bfb2f(f2bfb(ft[2 * j + 1]));
        ch[j] = hp;
        ch[12 + j] = hp;
        ch[6 + j] = pack2(l0, l1);
    }
    #pragma unroll
    for (int g = 0; g < 5; g++) {
        u32x4 v = {ch[4 * g], ch[4 * g + 1], ch[4 * g + 2], ch[4 * g + 3]};
        *(u32x4*)(latin + (((size_t)g * E_NUM + e) << 2)) = v;
    }
}

// ---------------- rho gather (4x unrolled j-loop, bitwise-same order) ----------------
__global__ __launch_bounds__(256) void k_rho_gather(
    const float* __restrict__ we, const int* __restrict__ rowstart,
    const float* __restrict__ ux, const float* __restrict__ uy,
    const float* __restrict__ uz,
    float* __restrict__ rho0, float* __restrict__ rho1) {
    int wv = (blockIdx.x * 256 + threadIdx.x) >> 6;
    int c = threadIdx.x & 63;
    if (wv >= NN) return;
    int start = rowstart[wv], end = rowstart[wv + 1];
    float s0 = 0.0f, sx = 0.0f, sy = 0.0f, sz = 0.0f;
    int j = start;
    for (; j + 4 <= end; j += 4) {
        float w0 = we[(size_t)j * 64 + c];
        float w1 = we[(size_t)(j + 1) * 64 + c];
        float w2 = we[(size_t)(j + 2) * 64 + c];
        float w3 = we[(size_t)(j + 3) * 64 + c];
        float a0 = ux[j], b0 = uy[j], g0 = uz[j];
        float a1 = ux[j + 1], b1 = uy[j + 1], g1 = uz[j + 1];
        float a2 = ux[j + 2], b2 = uy[j + 2], g2 = uz[j + 2];
        float a3 = ux[j + 3], b3 = uy[j + 3], g3 = uz[j + 3];
        s0 += w0; sx = fmaf(w0, a0, sx); sy = fmaf(w0, b0, sy); sz = fmaf(w0, g0, sz);
        s0 += w1; sx = fmaf(w1, a1, sx); sy = fmaf(w1, b1, sy); sz = fmaf(w1, g1, sz);
        s0 += w2; sx = fmaf(w2, a2, sx); sy = fmaf(w2, b2, sy); sz = fmaf(w2, g2, sz);
        s0 += w3; sx = fmaf(w3, a3, sx); sy = fmaf(w3, b3, sy); sz = fmaf(w3, g3, sz);
    }
    for (; j < end; j++) {
        float w0 = we[(size_t)j * 64 + c];
        float a0 = ux[j], b0 = uy[j], g0 = uz[j];
        s0 += w0; sx = fmaf(w0, a0, sx); sy = fmaf(w0, b0, sy); sz = fmaf(w0, g0, sz);
    }
    const float inv3 = 1.0f / 3.0f;
    rho0[(size_t)wv * 64 + c] = s0 * inv3;
    rho1[(size_t)wv * 192 + 3 * c + 0] = sx * inv3;
    rho1[(size_t)wv * 192 + 3 * c + 1] = sy * inv3;
    rho1[(size_t)wv * 192 + 3 * c + 2] = sz * inv3;
}

// =====================================================================
// MFMA MLP v22 = EXACT revert to v20 (R10, measured 405.3 us total —
// session best). R11 post-mortem: extending s_setprio to the short
// prologue/epilogue MFMA clusters REGRESSED +6% (120.5->128 us) — T5 is
// structure-conditional; prioritizing short between-barrier clusters
// removes the arbitration contrast that made the main-loop wrap a win.
// setprio stays ONLY on the long main-loop W1/W2 clusters.
// All levers measured-closed: occupancy (R2/R4: 128 regs/wave wall),
// barriers (R5), weight interleave (R6 win), layout+fusion (R7/R8 wins),
// wave mapping (R9: all-M optimal), setprio scope (R11). Remaining gap
// is dependency latency at 2 blocks/CU; next step would be a 32x32x16
// MFMA fragment rewrite (high risk without a refcheck loop).
// =====================================================================
template<int KSTEPS, int MODE, int HASLO, int FUSEWE, int STAGE>
__global__ __launch_bounds__(512, 4) void k_mlp(
    const u32* __restrict__ latin,
    const u16* __restrict__ W1pk, const u16* __restrict__ W2pk,
    const float* __restrict__ envb,
    u32* __restrict__ xout,
    const u16* __restrict__ wepk,
    float* __restrict__ webuf,
    const u32* __restrict__ xin,
    const u32* __restrict__ x0t,
    const int* __restrict__ ssend,
    const float* __restrict__ ux, const float* __restrict__ uy,
    const float* __restrict__ uz,
    const float* __restrict__ rho0A, const float* __restrict__ rho1A,
    const float* __restrict__ rho0B, const float* __restrict__ rho1B,
    const u16* __restrict__ wvpk, const u16* __restrict__ wmpk,
    const float* __restrict__ WoutP, const int* __restrict__ srecv,
    float* __restrict__ node_acc) {
    constexpr int ROWDW = KSTEPS * 16;
    constexpr int INAREG = KSTEPS * 4096;
    // transpose region (STAGE2): tbA 16640 + mb 16640 = 33280 >= 32768 hA dbuf
    constexpr int SMEMSZ = INAREG + ((STAGE == 2) ? (2 * 16640) : 32768);
    __shared__ __align__(16) char smem[SMEMSZ];
    u32* inA = (u32*)smem;
    u16* hA  = (u16*)(smem + INAREG);           // 2 x 16 KB double buffer (MLP)
    float* tbA = (float*)(smem + INAREG);       // 64x65 fp32 (a transpose, prologue)
    u16* mb   = (u16*)(smem + INAREG + 16640);  // m1/m2 interleaved bf16 (prologue)
    u32* mb32 = (u32*)(smem + INAREG + 16640);
    u32* xt0  = (u32*)(smem + INAREG + 16640);  // x0 tile (dies before mb writes)
    int lane = threadIdx.x & 63;
    int sub = threadIdx.x >> 6;
    int w = __builtin_amdgcn_readfirstlane(sub);
    int l15 = lane & 15, quad = lane >> 4;
    int e0 = blockIdx.x * 64;
    int e = e0 + lane;

    if (STAGE == 0) {
        // groups 5..7 of latin are identically zero (not stored)
        u32x4 v = (u32x4){0, 0, 0, 0};
        if (w < 5) v = *(const u32x4*)(latin + (((size_t)w * E_NUM + e) << 2));
        int slot = (w ^ lane) & 7;
        *(u32x4*)(&inA[lane * ROWDW + slot * 4]) = v;
        __syncthreads();
    } else {
        // stage xin chunk-group w -> inA (one dwordx4)
        {
            int c = w;
            u32x4 v = *(const u32x4*)(xin + (((size_t)c * E_NUM + e) << 2));
            int slot = (c & ~7) | ((c ^ lane) & 7);
            *(u32x4*)(&inA[lane * ROWDW + slot * 4]) = v;
        }
        if (STAGE == 2) {
            u32x4 v = *(const u32x4*)(x0t + (((size_t)w * E_NUM + e) << 2));
            int slot = (w ^ lane) & 7;
            *(u32x4*)(&xt0[lane * 32 + slot * 4]) = v;
        }
        __syncthreads();
        // mini-GEMM a = x0 @ Wv
        int mt = w & 3;
        int ntbA = (w >> 2) * 2;
        f32x4 accA[2];
        accA[0] = (f32x4){0.f, 0.f, 0.f, 0.f};
        accA[1] = (f32x4){0.f, 0.f, 0.f, 0.f};
        #pragma unroll
        for (int ks = 0; ks < 2; ks++) {
            int c = ks * 4 + quad;
            int m = mt * 16 + l15;
            bf16x8 af;
            if (STAGE == 1) {
                int slot = (c & ~7) | ((c ^ m) & 7);
                af = *(const bf16x8*)(&inA[m * ROWDW + slot * 4]);
            } else {
                int slot = (c ^ m) & 7;
                af = *(const bf16x8*)(&xt0[m * 32 + slot * 4]);
            }
            #pragma unroll
            for (int nti = 0; nti < 2; nti++) {
                int n = (ntbA + nti) * 16 + l15;
                const u16* bp = wvpk + ((((size_t)c << 6) + n) << 4);
                bf16x8 bh = *(const bf16x8*)(bp);
                accA[nti] = __builtin_amdgcn_mfma_f32_16x16x32_bf16(af, bh, accA[nti], 0, 0, 0);
                bf16x8 bl = *(const bf16x8*)(bp + 8);
                accA[nti] = __builtin_amdgcn_mfma_f32_16x16x32_bf16(af, bl, accA[nti], 0, 0, 0);
            }
        }
        // mini-GEMM m = x1 @ Wmix (STAGE==2)
        f32x4 accM[4];
        if (STAGE == 2) {
            #pragma unroll
            for (int i = 0; i < 4; i++) accM[i] = (f32x4){0.f, 0.f, 0.f, 0.f};
            int nbM = (w >> 2) * 4;
            #pragma unroll
            for (int ks = 0; ks < 2; ks++) {
                int c = ks * 4 + quad;
                int m = mt * 16 + l15;
                int slot = (c & ~7) | ((c ^ m) & 7);
                bf16x8 af = *(const bf16x8*)(&inA[m * ROWDW + slot * 4]);
                #pragma unroll
                for (int nti = 0; nti < 4; nti++) {
                    int n = (nbM + nti) * 16 + l15;
                    const u16* bp = wmpk + ((((size_t)c << 7) + n) << 4);
                    bf16x8 bh = *(const bf16x8*)(bp);
                    accM[nti] = __builtin_amdgcn_mfma_f32_16x16x32_bf16(af, bh, accM[nti], 0, 0, 0);
                    bf16x8 bl = *(const bf16x8*)(bp + 8);
                    accM[nti] = __builtin_amdgcn_mfma_f32_16x16x32_bf16(af, bl, accM[nti], 0, 0, 0);
                }
            }
        }
        __syncthreads();   // all GEMM LDS reads done (xt0 dead)
        // ---- single transpose round: a -> tbA (fp32), m1/m2 -> mb (bf16 halves)
        #pragma unroll
        for (int nti = 0; nti < 2; nti++) {
            #pragma unroll
            for (int r = 0; r < 4; r++) {
                int rowD = mt * 16 + quad * 4 + r;
                int colD = (ntbA + nti) * 16 + l15;
                tbA[colD * 65 + rowD] = accA[nti][r];
            }
        }
        if (STAGE == 2) {
            int sel = (w >= 4) ? 1 : 0;
            #pragma unroll
            for (int nti = 0; nti < 4; nti++) {
                #pragma unroll
                for (int r = 0; r < 4; r++) {
                    int rowD = mt * 16 + quad * 4 + r;
                    int colD = nti * 16 + l15;
                    mb[((colD * 65 + rowD) << 1) + sel] = (u16)f2bfb(accM[nti][r]);
                }
            }
        }
        __syncthreads();
        int c0 = w * 8;
        float av[8], m1v[8], m2v[8];
        #pragma unroll
        for (int i = 0; i < 8; i++) av[i] = tbA[(c0 + i) * 65 + lane];
        if (STAGE == 2) {
            #pragma unroll
            for (int i = 0; i < 8; i++) {
                u32 pv = mb32[(c0 + i) * 65 + lane];
                m1v[i] = bfb2f(pv & 0xffffu);
                m2v[i] = bfb2f(pv >> 16);
            }
        }
        // per-lane tp math + gathers
        int s = ssend[e];
        float u0 = ux[e], u1 = uy[e], u2 = uz[e];
        float ts[8], rr[8];
        if (STAGE == 1) {
            const float* r1 = rho1A + (size_t)s * 192;
            const float* r0 = rho0A + (size_t)s * 64;
            #pragma unroll
            for (int i = 0; i < 8; i++) {
                int c = c0 + i;
                float dot = u0 * r1[3 * c] + u1 * r1[3 * c + 1] + u2 * r1[3 * c + 2];
                ts[i] = av[i] * dot;
                rr[i] = r0[c];
            }
        } else {
            const float* r1A = rho1A + (size_t)s * 192;
            const float* r0A = rho0A + (size_t)s * 64;
            const float* r1B = rho1B + (size_t)s * 192;
            const float* r0B = rho0B + (size_t)s * 64;
            #pragma unroll
            for (int i = 0; i < 8; i++) {
                int c = c0 + i;
                float v0 = av[i] * u0, v1 = av[i] * u1, v2 = av[i] * u2;
                float aA0 = r1A[3 * c], aA1 = r1A[3 * c + 1], aA2 = r1A[3 * c + 2];
                float rc = r0A[c];
                float w0 = m1v[i] * v0 * rc + m2v[i] * (v1 * aA2 - v2 * aA1);
                float w1 = m1v[i] * v1 * rc + m2v[i] * (v2 * aA0 - v0 * aA2);
                float w2 = m1v[i] * v2 * rc + m2v[i] * (v0 * aA1 - v1 * aA0);
                ts[i] = w0 * r1B[3 * c] + w1 * r1B[3 * c + 1] + w2 * r1B[3 * c + 2];
                rr[i] = r0B[c];
            }
        }
        u32x4 tv, rv;
        #pragma unroll
        for (int j = 0; j < 4; j++) {
            tv[j] = pack2(ts[2 * j], ts[2 * j + 1]);
            rv[j] = pack2(rr[2 * j], rr[2 * j + 1]);
        }
        {
            int c = 8 + w;
            int slot = (c & ~7) | ((c ^ lane) & 7);
            *(u32x4*)(&inA[lane * ROWDW + slot * 4]) = tv;
        }
        {
            int c = 16 + w;
            int slot = (c & ~7) | ((c ^ lane) & 7);
            *(u32x4*)(&inA[lane * ROWDW + slot * 4]) = rv;
        }
        __syncthreads();
    }

    // ======== main MLP: software-pipelined, hA double-buffered ========
    f32x4 acc2[2];
    acc2[0] = (f32x4){0.f, 0.f, 0.f, 0.f};
    acc2[1] = (f32x4){0.f, 0.f, 0.f, 0.f};
    int nt2 = w & 3;
    int mt2a = (w >> 2) * 2;
    int p = 0;

    #pragma unroll
    for (int it = 0; it < 5; it++) {
        f32x4 acc[4];
        if (it < 4) {
            #pragma unroll
            for (int mt = 0; mt < 4; mt++) acc[mt] = (f32x4){0.f, 0.f, 0.f, 0.f};
            __builtin_amdgcn_s_setprio(1);
            #pragma unroll
            for (int ks = 0; ks < KSTEPS; ks++) {
                int c = ks * 4 + quad;
                bf16x8 afr[4];
                #pragma unroll
                for (int mt = 0; mt < 4; mt++) {
                    int m = mt * 16 + l15;
                    int slot = (c & ~7) | ((c ^ m) & 7);
                    afr[mt] = *(const bf16x8*)(&inA[m * ROWDW + slot * 4]);
                }
                int n = it * 128 + w * 16 + l15;
                const u16* bp = W1pk + ((((size_t)c << 9) + n) << 4);
                bf16x8 bh = *(const bf16x8*)(bp);
                #pragma unroll
                for (int mt = 0; mt < 4; mt++)
                    acc[mt] = __builtin_amdgcn_mfma_f32_16x16x32_bf16(afr[mt], bh, acc[mt], 0, 0, 0);
                if (HASLO) {
                    bf16x8 bl = *(const bf16x8*)(bp + 8);
                    #pragma unroll
                    for (int mt = 0; mt < 4; mt++)
                        acc[mt] = __builtin_amdgcn_mfma_f32_16x16x32_bf16(afr[mt], bl, acc[mt], 0, 0, 0);
                }
            }
            __builtin_amdgcn_s_setprio(0);
        }
        if (it > 0) {
            const u16* hAr = hA + (p ^ 1) * 8192;
            __builtin_amdgcn_s_setprio(1);
            #pragma unroll
            for (int ks = 0; ks < 4; ks++) {
                int c = ks * 4 + quad;
                int m0 = mt2a * 16 + l15;
                int m1i = m0 + 16;
                int s0 = (c & 8) | ((c ^ m0) & 7);
                int s1 = (c & 8) | ((c ^ m1i) & 7);
                bf16x8 a0 = *(const bf16x8*)(&hAr[m0 * 128 + s0 * 8]);
                bf16x8 a1 = *(const bf16x8*)(&hAr[m1i * 128 + s1 * 8]);
                const u16* bp = W2pk + ((((size_t)((it - 1) * 16 + c) << 6) + nt2 * 16 + l15) << 4);
                bf16x8 bh = *(const bf16x8*)(bp);
                acc2[0] = __builtin_amdgcn_mfma_f32_16x16x32_bf16(a0, bh, acc2[0], 0, 0, 0);
                acc2[1] = __builtin_amdgcn_mfma_f32_16x16x32_bf16(a1, bh, acc2[1], 0, 0, 0);
                bf16x8 bl = *(const bf16x8*)(bp + 8);
                acc2[0] = __builtin_amdgcn_mfma_f32_16x16x32_bf16(a0, bl, acc2[0], 0, 0, 0);
                acc2[1] = __builtin_amdgcn_mfma_f32_16x16x32_bf16(a1, bl, acc2[1], 0, 0, 0);
            }
            __builtin_amdgcn_s_setprio(0);
        }
        if (it < 4) {
            u16* hAw = hA + p * 8192;
            int kh = w * 16 + l15;
            int c = kh >> 3;
            #pragma unroll
            for (int mt = 0; mt < 4; mt++) {
                #pragma unroll
                for (int r = 0; r < 4; r++) {
                    int m = mt * 16 + quad * 4 + r;
                    float s = silu_fast(acc[mt][r]);
                    int slot = (c & 8) | ((c ^ m) & 7);
                    hAw[m * 128 + slot * 8 + (kh & 7)] = (u16)f2bfb(s);
                }
            }
            __syncthreads();
        }
        p ^= 1;
    }
    // read xprev (chunks 0..7 hold current-layer x) from LDS before epi overlay
    float xo[8];
    if (MODE) {
        int c = w;
        int slot = (c & ~7) | ((c ^ lane) & 7);
        #pragma unroll
        for (int i = 0; i < 4; i++) {
            u32 pv = inA[lane * ROWDW + slot * 4 + i];
            xo[2 * i]     = bfb2f(pv & 0xffffu);
            xo[2 * i + 1] = bfb2f(pv >> 16);
        }
    }
    __syncthreads();
    float* epi = (float*)inA;   // 64 x 65 fp32 overlay (16640 B of INAREG)
    #pragma unroll
    for (int mi = 0; mi < 2; mi++) {
        #pragma unroll
        for (int r = 0; r < 4; r++) {
            int m = (mt2a + mi) * 16 + quad * 4 + r;
            int c = nt2 * 16 + l15;
            epi[c * 65 + m] = acc2[mi][r];
        }
    }
    __syncthreads();
    float env = envb[e];
    const float is2 = 0.70710678118654752f;
    float resv[8];
    #pragma unroll
    for (int i = 0; i < 8; i++) {
        int c = w * 8 + i;
        float v = epi[c * 65 + lane];
        float res;
        if (MODE) res = (xo[i] + v * env) * is2;
        else      res = v * env;
        resv[i] = res;
        if (FUSEWE) epi[c * 65 + lane] = res;
    }
    if (STAGE != 2) {
        u32x4 tv;
        #pragma unroll
        for (int j = 0; j < 4; j++) tv[j] = pack2(resv[2 * j], resv[2 * j + 1]);
        *(u32x4*)(xout + (((size_t)w * E_NUM + e) << 2)) = tv;
    }
    if (STAGE == 2) {
        // fused readout: e_edge = dot(x1, Wout) * env / 3 -> node_acc[srecv]
        float* red = (float*)(smem + 20480);   // disjoint from epi (<16640)
        float pd = 0.0f;
        #pragma unroll
        for (int i = 0; i < 8; i++) pd = fmaf(resv[i], WoutP[w * 8 + i], pd);
        red[w * 64 + lane] = pd;
        __syncthreads();
        if (w == 0) {
            float sum = 0.0f;
            #pragma unroll
            for (int ww = 0; ww < 8; ww++) sum += red[ww * 64 + lane];
            atomicAdd(&node_acc[srecv[e]], sum * env * (1.0f / 3.0f));
        }
    }
    if (FUSEWE) {
        __syncthreads();
        int mt = w & 3;
        int ntb = (w >> 2) * 2;
        f32x4 accw[2];
        accw[0] = (f32x4){0.f, 0.f, 0.f, 0.f};
        accw[1] = (f32x4){0.f, 0.f, 0.f, 0.f};
        #pragma unroll
        for (int ks = 0; ks < 2; ks++) {
            bf16x8 af;
            #pragma unroll
            for (int j = 0; j < 8; j++)
                af[j] = (short)f2bfb(epi[(ks * 32 + quad * 8 + j) * 65 + mt * 16 + l15]);
            #pragma unroll
            for (int nti = 0; nti < 2; nti++) {
                int n4 = (ntb + nti) * 16 + l15;
                const u16* bp = wepk + ((((size_t)(ks * 4 + quad) << 6) + n4) << 4);
                bf16x8 bh = *(const bf16x8*)(bp);
                accw[nti] = __builtin_amdgcn_mfma_f32_16x16x32_bf16(af, bh, accw[nti], 0, 0, 0);
                bf16x8 bl = *(const bf16x8*)(bp + 8);
                accw[nti] = __builtin_amdgcn_mfma_f32_16x16x32_bf16(af, bl, accw[nti], 0, 0, 0);
            }
        }
        #pragma unroll
        for (int nti = 0; nti < 2; nti++) {
            #pragma unroll
            for (int r = 0; r < 4; r++) {
                int rowD = mt * 16 + quad * 4 + r;
                int colD = (ntb + nti) * 16 + l15;
                webuf[(size_t)(e0 + rowD) * 64 + colD] = accw[nti][r];
            }
        }
    }
}

__global__ void k_out(const float* __restrict__ node_acc, void* __restrict__ out,
                      const int* __restrict__ flag) {
    int n = blockIdx.x * 256 + threadIdx.x;
    if (n >= NN) return;
    float v = node_acc[n];
    if (*flag) ((float*)out)[n] = v;
    else       ((u16*)out)[n] = (u16)f2bfb(v);
}

extern "C" void kernel_launch(void* const* d_in, const int* in_sizes, int n_in,
                              void* d_out, int out_size, void* d_ws, size_t ws_size,
                              hipStream_t stream) {
    const void* posr   = d_in[0];
    const void* Wemb1r = d_in[1];
    const void* Wemb2r = d_in[2];
    const void* Wvr    = d_in[3];
    const void* Wenvr  = d_in[4];
    const void* Wlat1r = d_in[5];
    const void* Wlat2r = d_in[6];
    const void* Wmixr  = d_in[7];
    const void* Woutr  = d_in[8];
    const int* species   = (const int*)d_in[9];
    const int* senders   = (const int*)d_in[10];
    const int* receivers = (const int*)d_in[11];

    char* p = (char*)d_ws;
    auto alloc = [&](size_t bytes) -> void* {
        void* rp = (void*)p;
        p += (bytes + 255) & ~(size_t)255;
        return rp;
    };
    int*   flag  = (int*)alloc(4);
    float* wbuf  = (float*)alloc(359792 * 4);
    float* posf  = wbuf;
    float* Wemb1 = wbuf + 30000;
    float* Wemb2 = wbuf + 36144;
    float* Wv    = wbuf + 68912;
    float* Wenv  = wbuf + 73008;
    float* Wlat1 = wbuf + 81200;
    float* Wlat2 = wbuf + 277808;
    float* Wmix  = wbuf + 343344;
    float* Wout  = wbuf + 359728;
    const size_t E = E_NUM;
    float* ux   = (float*)alloc(E * 4);
    float* uy   = (float*)alloc(E * 4);
    float* uz   = (float*)alloc(E * 4);
    float* envb = (float*)alloc(E * 4);
    float* rho0A = (float*)alloc((size_t)NN * 64 * 4);
    float* rho1A = (float*)alloc((size_t)NN * 192 * 4);
    float* rho0B = (float*)alloc((size_t)NN * 64 * 4);
    float* rho1B = (float*)alloc((size_t)NN * 192 * 4);
    float* node_acc = (float*)alloc((size_t)NN * 4);
    int* counts    = (int*)alloc((size_t)NN * 4);
    int* rowstart  = (int*)alloc((size_t)(NN + 1) * 4);
    int* cursor    = (int*)alloc((size_t)NN * 4);
    int* edge_list = (int*)alloc(E * 4);
    int* ssend     = (int*)alloc(E * 4);
    int* srecv     = (int*)alloc(E * 4);
    void* unionbuf = alloc(96 * E * 4);
    u32*   latin = (u32*)unionbuf;
    float* webuf = (float*)unionbuf + (size_t)32 * E;
    u32* x0 = (u32*)alloc(32 * E * 4);   // group-packed: 8 groups x E x u32x4
    u32* x1 = (u32*)alloc(32 * E * 4);
    // interleaved hi/lo packed weights
    u16* w1pk = (u16*)alloc(2 * 196608 * 2);   // 2 layers x 192x512 x (hi+lo)
    u16* w2pk = (u16*)alloc(2 * 65536 * 2);    // 2 layers x 512x64 x (hi+lo)
    u16* e1pk = (u16*)alloc(65536 * 2);        // emb W1 (hi-only slots used)
    u16* e2pk = (u16*)alloc(65536 * 2);        // emb W2
    u16* we0pk = (u16*)alloc(8192 * 2);
    u16* we1pk = (u16*)alloc(8192 * 2);
    u16* wvpk  = (u16*)alloc(8192 * 2);
    u16* wmpk  = (u16*)alloc(16384 * 2);

    hipMemsetAsync(flag, 0, 4, stream);
    hipMemsetAsync(counts, 0, (size_t)NN * 4, stream);
    hipMemsetAsync(node_acc, 0, (size_t)NN * 4, stream);

    k_detect<<<(15000 + 255) / 256, 256, 0, stream>>>((const u16*)posr, flag);

    // fused: dual-dtype ingest + sender histogram
    k_prep1<<<2031, 256, 0, stream>>>(
        posr, Wemb1r, Wemb2r, Wvr, Wenvr, Wlat1r, Wlat2r, Wmixr, Woutr,
        wbuf, flag, senders, counts);

    // scan writes rowstart AND cursor
    k_scan<<<1, 1024, 0, stream>>>(counts, rowstart, cursor);

    // fused: CSR fill + all weight packs
    k_prep2<<<1985, 256, 0, stream>>>(
        senders, cursor, edge_list,
        Wemb1, Wemb2, Wenv, Wv, Wmix, Wlat1, Wlat2,
        e1pk, e2pk, we0pk, we1pk, wvpk, wmpk, w1pk, w2pk);

    // embedding + fused layer-0 we
    k_geom<<<625, 256, 0, stream>>>(posf, species, senders, receivers, edge_list,
                                    ssend, srecv, ux, uy, uz, envb, latin);
    k_mlp<2, 0, 0, 1, 0><<<2500, 512, 0, stream>>>(
        latin, e1pk, e2pk, envb, x0, we0pk, webuf,
        nullptr, nullptr, nullptr, nullptr, nullptr, nullptr,
        nullptr, nullptr, nullptr, nullptr, nullptr, nullptr,
        nullptr, nullptr, nullptr);

    // layer 0 (fused stage) + fused layer-1 we
    k_rho_gather<<<2500, 256, 0, stream>>>(webuf, rowstart, ux, uy, uz,
                                           rho0A, rho1A);
    k_mlp<6, 1, 1, 1, 1><<<2500, 512, 0, stream>>>(
        nullptr, w1pk, w2pk, envb, x1, we1pk, webuf,
        x0, nullptr, ssend, ux, uy, uz, rho0A, rho1A, nullptr, nullptr,
        wvpk, nullptr, nullptr, nullptr, nullptr);

    // layer 1 (fused stage, compact m transpose) + FUSED READOUT
    k_rho_gather<<<2500, 256, 0, stream>>>(webuf, rowstart, ux, uy, uz,
                                           rho0B, rho1B);
    k_mlp<6, 1, 1, 0, 2><<<2500, 512, 0, stream>>>(
        nullptr, w1pk + 196608, w2pk + 65536, envb, nullptr, nullptr, nullptr,
        x1, x0, ssend, ux, uy, uz, rho0A, rho1A, rho0B, rho1B,
        wvpk, wmpk, Wout, srecv, node_acc);

    k_out<<<(NN + 255) / 256, 256, 0, stream>>>(node_acc, d_out, flag);
}